// Round 1
// 429.345 us; speedup vs baseline: 1.1297x; 1.1297x over previous
//
#include <hip/hip_runtime.h>

// SubgraphPooling via counting-sort + segmented reduction.
// out[s,:] = mean over edges e with sid[e]==s of feat[nid[e],:]
// N_NODES=100000, D=128, E=2000000, N_SEG=250000
//
// R5 changes vs 481µs baseline:
//  - hist stores its atomicAdd return as rank[e] (8MB NT stream) -> reorder is
//    atomic-free (was: 2M more atomic-with-return on cur[]). Halves atomics.
//  - reduce: 8-deep clamped prefetch (all row loads issued before any acc) to
//    lift outstanding VMEM per half-wave from 2 to 8; NT store for the 128MB
//    output so it doesn't evict the 51MB feat table (20x reuse) from L2.

constexpr int N_SEG  = 250000;
constexpr int SCAN_CHUNK  = 1024;                                   // 256 thr x 4
constexpr int SCAN_BLOCKS = (N_SEG + SCAN_CHUNK - 1) / SCAN_CHUNK;  // 245

typedef float nt4 __attribute__((ext_vector_type(4)));

// ---- rank-path workspace layout (needs >= 20 MiB) ----
// [0,1MB) cnt | [1MB,2MB) off | [2MB,2MB+1KB) bsum | [4MB,12MB) rank | [12MB,20MB) sorted
#define RP_CNT(ws)     ((int*)((char*)(ws) + 0))
#define RP_OFF(ws)     ((int*)((char*)(ws) + (1u<<20)))
#define RP_BSUM(ws)    ((int*)((char*)(ws) + (2u<<20)))
#define RP_RANK(ws)    ((int*)((char*)(ws) + (4u<<20)))
#define RP_SORTED(ws)  ((int*)((char*)(ws) + (12u<<20)))

// ---- fallback layout (old, needs >= 12 MiB) ----
#define WS_CNT(ws)     ((int*)((char*)(ws) + 0))
#define WS_CUR(ws)     ((int*)((char*)(ws) + (1u<<20)))
#define WS_OFF(ws)     ((int*)((char*)(ws) + (2u<<20)))
#define WS_BSUM(ws)    ((int*)((char*)(ws) + (3u<<20)))
#define WS_SORTED(ws)  ((int*)((char*)(ws) + (4u<<20)))

// Histogram; optionally emit per-edge within-segment rank (atomicAdd return).
__global__ __launch_bounds__(256) void sp_hist_rank(
    const int* __restrict__ sid, int* __restrict__ cnt,
    int* __restrict__ rank, int n)
{
    int i = blockIdx.x * blockDim.x + threadIdx.x;
    if (i >= n) return;
    int s = __builtin_nontemporal_load(&sid[i]);
    int r = atomicAdd(&cnt[s], 1);
    if (rank) __builtin_nontemporal_store(r, &rank[i]);
}

// Per-chunk exclusive scan (1024 elems / block); emit chunk totals.
__global__ __launch_bounds__(256) void sp_scan_local(
    const int* __restrict__ cnt, int* __restrict__ off, int* __restrict__ bsum)
{
    __shared__ int sh[256];
    int tid  = threadIdx.x;
    int base = blockIdx.x * SCAN_CHUNK + tid * 4;
    int v0 = (base + 0 < N_SEG) ? cnt[base + 0] : 0;
    int v1 = (base + 1 < N_SEG) ? cnt[base + 1] : 0;
    int v2 = (base + 2 < N_SEG) ? cnt[base + 2] : 0;
    int v3 = (base + 3 < N_SEG) ? cnt[base + 3] : 0;
    sh[tid] = v0 + v1 + v2 + v3;
    __syncthreads();
    for (int o = 1; o < 256; o <<= 1) {
        int t = (tid >= o) ? sh[tid - o] : 0;
        __syncthreads();
        sh[tid] += t;
        __syncthreads();
    }
    int excl = (tid > 0) ? sh[tid - 1] : 0;
    if (base + 0 < N_SEG) off[base + 0] = excl;
    if (base + 1 < N_SEG) off[base + 1] = excl + v0;
    if (base + 2 < N_SEG) off[base + 2] = excl + v0 + v1;
    if (base + 3 < N_SEG) off[base + 3] = excl + v0 + v1 + v2;
    if (tid == 255) bsum[blockIdx.x] = sh[255];
}

// Exclusive scan of the 245 chunk totals — one block, LDS scan.
__global__ __launch_bounds__(256) void sp_scan_blocks(int* __restrict__ bsum)
{
    __shared__ int sh[256];
    int tid = threadIdx.x;
    int v = (tid < SCAN_BLOCKS) ? bsum[tid] : 0;
    sh[tid] = v;
    __syncthreads();
    for (int o = 1; o < 256; o <<= 1) {
        int t = (tid >= o) ? sh[tid - o] : 0;
        __syncthreads();
        sh[tid] += t;
        __syncthreads();
    }
    if (tid < SCAN_BLOCKS) bsum[tid] = sh[tid] - v;   // inclusive -> exclusive
}

// Atomic-free reorder: position comes from the precomputed rank.
__global__ __launch_bounds__(256) void sp_reorder_rank(
    const int* __restrict__ nid, const int* __restrict__ sid,
    const int* __restrict__ off, const int* __restrict__ bsum,
    const int* __restrict__ rank, int* __restrict__ sorted_nid, int n)
{
    int i = blockIdx.x * blockDim.x + threadIdx.x;
    if (i >= n) return;
    int s = __builtin_nontemporal_load(&sid[i]);
    int r = __builtin_nontemporal_load(&rank[i]);
    int v = __builtin_nontemporal_load(&nid[i]);
    sorted_nid[off[s] + bsum[s >> 10] + r] = v;
}

// Fallback reorder (old path): atomic cursor per segment.
__global__ __launch_bounds__(256) void sp_reorder_atomic(
    const int* __restrict__ nid, const int* __restrict__ sid,
    const int* __restrict__ off, const int* __restrict__ bsum,
    int* __restrict__ cur, int* __restrict__ sorted_nid, int n)
{
    int i = blockIdx.x * blockDim.x + threadIdx.x;
    if (i >= n) return;
    int s = sid[i];
    int pos = off[s] + bsum[s >> 10] + atomicAdd(&cur[s], 1);
    sorted_nid[pos] = nid[i];
}

// Reduce: one half-wave (32 lanes) per segment; lane = one float4 chunk.
// 8-deep clamped prefetch: all row loads of a chunk are issued before any
// accumulate, so vmcnt never forces a full drain between dependent loads.
__global__ __launch_bounds__(256) void sp_reduce(
    const float4* __restrict__ feat4,      // [N_NODES][32] float4
    const int* __restrict__ sorted_nid,
    const int* __restrict__ off,
    const int* __restrict__ bsum,
    const int* __restrict__ cnt,
    float4* __restrict__ out4)             // [N_SEG][32] float4
{
    int seg  = blockIdx.x * 8 + (threadIdx.x >> 5);
    int lane = threadIdx.x & 31;
    if (seg >= N_SEG) return;

    int n   = cnt[seg];
    int beg = off[seg] + bsum[seg >> 10];
    int m   = (n < 32) ? n : 32;
    int myid = (lane < m) ? sorted_nid[beg + lane] : 0;

    float4 acc0 = make_float4(0.f, 0.f, 0.f, 0.f);
    float4 acc1 = make_float4(0.f, 0.f, 0.f, 0.f);

    if (m > 0) {
        int last = m - 1;
        for (int j0 = 0; j0 < m; j0 += 8) {
            // issue 8 loads up front; indices past the end clamp to the last
            // valid row (same line -> MSHR-merged, no extra HBM traffic).
            int id[8];
#pragma unroll
            for (int k = 0; k < 8; ++k) {
                int jj = j0 + k;
                id[k] = __shfl(myid, (jj < last) ? jj : last, 32);
            }
            float4 b[8];
#pragma unroll
            for (int k = 0; k < 8; ++k)
                b[k] = feat4[(size_t)id[k] * 32 + lane];
#pragma unroll
            for (int k = 0; k < 8; ++k) {
                if (j0 + k < m) {
                    if (k & 1) {
                        acc1.x += b[k].x; acc1.y += b[k].y;
                        acc1.z += b[k].z; acc1.w += b[k].w;
                    } else {
                        acc0.x += b[k].x; acc0.y += b[k].y;
                        acc0.z += b[k].z; acc0.w += b[k].w;
                    }
                }
            }
        }
        // pathological n > 32 fallback (Poisson(8): effectively never)
        for (int k = 32; k < n; ++k) {
            int nk = sorted_nid[beg + k];
            float4 a = feat4[(size_t)nk * 32 + lane];
            acc0.x += a.x; acc0.y += a.y; acc0.z += a.z; acc0.w += a.w;
        }
    }

    float inv = 1.0f / (float)((n > 0) ? n : 1);
    nt4 r;
    r.x = (acc0.x + acc1.x) * inv;
    r.y = (acc0.y + acc1.y) * inv;
    r.z = (acc0.z + acc1.z) * inv;
    r.w = (acc0.w + acc1.w) * inv;
    // NT store: don't let the 128MB output evict the 51MB feat table from L2.
    __builtin_nontemporal_store(
        r, reinterpret_cast<nt4*>(out4) + (size_t)seg * 32 + lane);
}

extern "C" void kernel_launch(void* const* d_in, const int* in_sizes, int n_in,
                              void* d_out, int out_size, void* d_ws, size_t ws_size,
                              hipStream_t stream) {
    const float* feat = (const float*)d_in[0];
    const int*   nid  = (const int*)d_in[1];
    const int*   sid  = (const int*)d_in[2];
    const int n_edges = in_sizes[1];

    int eb = (n_edges + 255) / 256;
    int rb = (N_SEG + 7) / 8;   // 8 segments (half-waves) per 256-thread block

    if (ws_size >= (size_t)(20u << 20)) {
        // rank path: hist emits ranks, reorder is atomic-free
        int* cnt    = RP_CNT(d_ws);
        int* off    = RP_OFF(d_ws);
        int* bsum   = RP_BSUM(d_ws);
        int* rank   = RP_RANK(d_ws);
        int* sorted = RP_SORTED(d_ws);

        hipMemsetAsync(d_ws, 0, (size_t)(1u << 20), stream);   // cnt only
        sp_hist_rank<<<eb, 256, 0, stream>>>(sid, cnt, rank, n_edges);
        sp_scan_local<<<SCAN_BLOCKS, 256, 0, stream>>>(cnt, off, bsum);
        sp_scan_blocks<<<1, 256, 0, stream>>>(bsum);
        sp_reorder_rank<<<eb, 256, 0, stream>>>(nid, sid, off, bsum, rank,
                                                sorted, n_edges);
        sp_reduce<<<rb, 256, 0, stream>>>((const float4*)feat, sorted, off,
                                          bsum, cnt, (float4*)d_out);
    } else {
        // fallback: previous verified path (atomic cursor), needs 12 MiB
        int* cnt    = WS_CNT(d_ws);
        int* cur    = WS_CUR(d_ws);
        int* off    = WS_OFF(d_ws);
        int* bsum   = WS_BSUM(d_ws);
        int* sorted = WS_SORTED(d_ws);

        hipMemsetAsync(d_ws, 0, (size_t)(2u << 20), stream);   // cnt + cur
        sp_hist_rank<<<eb, 256, 0, stream>>>(sid, cnt, nullptr, n_edges);
        sp_scan_local<<<SCAN_BLOCKS, 256, 0, stream>>>(cnt, off, bsum);
        sp_scan_blocks<<<1, 256, 0, stream>>>(bsum);
        sp_reorder_atomic<<<eb, 256, 0, stream>>>(nid, sid, off, bsum, cur,
                                                  sorted, n_edges);
        sp_reduce<<<rb, 256, 0, stream>>>((const float4*)feat, sorted, off,
                                          bsum, cnt, (float4*)d_out);
    }
}